// Round 7
// baseline (43.681 us; speedup 1.0000x reference)
//
#include <hip/hip_runtime.h>

typedef float  f32x4  __attribute__((ext_vector_type(4)));
typedef float  f32x2a __attribute__((ext_vector_type(2), aligned(4)));
typedef __bf16 bf16x8 __attribute__((ext_vector_type(8)));
typedef short  short8 __attribute__((ext_vector_type(8)));

#define F      65
#define NTT    17           // 16 D-tiles of 16 cols + 1 S-tile
#define KS3    3            // K padded (65 + bias) -> 96, 3 ksteps of 32
#define RPB    128          // rows per block (4 waves x 32 rows)
#define PADROW 68           // LDS row stride in dwords (272 B -> 16B-aligned frags)
#define SLABDW (32 * PADROW)
#define NEGL2E -1.4426950408889634f

__device__ __forceinline__ float fast_sigmoid(float x) {
  float e = __builtin_amdgcn_exp2f(NEGL2E * x);
  return __builtin_amdgcn_rcpf(1.0f + e);
}
// acc pre-scaled by -log2e: sigmoid = rcp(1 + exp2(acc))
__device__ __forceinline__ float sig_prescaled(float a) {
  return __builtin_amdgcn_rcpf(1.0f + __builtin_amdgcn_exp2f(a));
}
template<int CTRL>
__device__ __forceinline__ float dpp_mov(float v) {
  return __builtin_bit_cast(float,
    __builtin_amdgcn_update_dpp(0, __builtin_bit_cast(int, v), CTRL, 0xF, 0xF, true));
}
__device__ __forceinline__ float reduce16(float v) {
  v += dpp_mov<0xB1>(v);                   // xor1
  v += dpp_mov<0x4E>(v);                   // xor2
  v += dpp_mov<0x141>(v);                  // xor4 (row_half_mirror)
  v += dpp_mov<0x140>(v);                  // xor8 (row_mirror)
  return v;
}

// ---- prepass: fragment-ordered bf16 W blob; D-part pre-scaled by -log2e ----
// chunk = (t*3+s)*64 + lane ; lane holds 8 bf16 of B:
//   col n = 16*t + (lane&15), k = 32*s + 8*(lane>>4) + j   (k==65 is bias row)
__global__ void prep_w(const float* __restrict__ W_S, const float* __restrict__ b_S,
                       const float* __restrict__ W_D, const float* __restrict__ b_D,
                       unsigned short* __restrict__ wsb) {
  int b = blockIdx.x;              // 0..50 = t*3+s
  int t = b / 3, s = b % 3;
  int l = threadIdx.x;
  int c = l & 15, q = l >> 4;
  short8 out;
#pragma unroll
  for (int j = 0; j < 8; ++j) {
    int k = 32 * s + 8 * q + j;
    float v = 0.0f;
    if (t < 16) {
      int n = 16 * t + c;
      if (k < F)       v = NEGL2E * W_D[n * F + k];
      else if (k == F) v = NEGL2E * b_D[n];
    } else if (c < 8) {
      if (k < F)       v = W_S[c * F + k];
      else if (k == F) v = b_S[c];
    }
    unsigned int u = __builtin_bit_cast(unsigned int, v);
    u += 0x7FFFu + ((u >> 16) & 1u);
    out[j] = (short)(u >> 16);
  }
  reinterpret_cast<short8*>(wsb)[b * 64 + l] = out;
}

// ---- main fused kernel: coalesced phi staging via wave-private LDS slab ----
__launch_bounds__(256, 4)   // reg cap 128; LDS (47 KB) limits to 3 blocks/CU
__global__ void mpuf_main(const float* __restrict__ phi,
                          const unsigned short* __restrict__ wsb,
                          float* __restrict__ out_ans,
                          float* __restrict__ out_rel) {
  __shared__ __align__(16) float ldsPhi[4 * SLABDW];   // 34816 B
  __shared__ float soutv[RPB][9];                      // 4608 B
  __shared__ float mtrec[RPB][17];                     // 8704 B

  const int tid  = threadIdx.x;
  const int wave = tid >> 6;
  const int l    = tid & 63;
  const int c    = l & 15;                 // col-in-tile / row-in-A-fragment
  const int q    = l >> 4;                 // k-group / C-row quad
  const int wrow = wave * 32;
  const int brow = blockIdx.x * RPB;

  // ---- coalesced staging loads: 9 x dwordx4, 1 KB contiguous per instr ----
  // wave slab = rows [wrow, wrow+32) = 8320 B, 16B-aligned (multiple of 8320)
  const float* slab = phi + (size_t)(brow + wrow) * F;
  f32x4 st[9];
#pragma unroll
  for (int i = 0; i < 9; ++i) {
    if (i < 8 || l < 8)                    // 520 chunks = 8*64 + 8
      st[i] = *reinterpret_cast<const f32x4*>(slab + 4 * (l + 64 * i));
  }

  // blob prefetch while staging loads are in flight
  const short8* wsv = reinterpret_cast<const short8*>(wsb);
  short8 bcur[3], bnxt[3];
#pragma unroll
  for (int s = 0; s < 3; ++s) bcur[s] = wsv[(16 * KS3 + s) * 64 + l];
#pragma unroll
  for (int s = 0; s < 3; ++s) bnxt[s] = wsv[s * 64 + l];   // tile 0

  // ---- scatter-write into pad-68 LDS slab (rows 272 B apart) --------------
  float* myslab = &ldsPhi[wave * SLABDW];
#pragma unroll
  for (int i = 0; i < 9; ++i) {
    if (i < 8 || l < 8) {
#pragma unroll
      for (int j = 0; j < 4; ++j) {
        int gi = 4 * (l + 64 * i) + j;     // dword index in unpadded slab
        myslab[gi + 3 * (gi / 65)] = st[i][j];
      }
    }
  }
  // wave-private slab: same-wave ds ordering via lgkmcnt, no barrier.

  // ---- A fragments from LDS (16B-aligned ds_read_b128) --------------------
  bf16x8 af0[3], af1[3];
#pragma unroll
  for (int h = 0; h < 2; ++h) {
    bf16x8* af = h ? af1 : af0;
    const float* rb = &myslab[PADROW * (c + 16 * h)];
#pragma unroll
    for (int s = 0; s < 2; ++s) {
      f32x4 lo = *reinterpret_cast<const f32x4*>(rb + 32 * s + 8 * q);
      f32x4 hi = *reinterpret_cast<const f32x4*>(rb + 32 * s + 8 * q + 4);
      bf16x8 v;
#pragma unroll
      for (int j = 0; j < 4; ++j) {
        v[j]     = (__bf16)lo[j];
        v[j + 4] = (__bf16)hi[j];
      }
      af[s] = v;
    }
    bf16x8 v = {};
    if (q == 0) { v[0] = (__bf16)rb[64]; v[1] = (__bf16)1.0f; }  // k=64 + bias
    af[2] = v;
  }

  // ---- S tile (unscaled): Sdelta with bias folded --------------------------
  f32x4 aS0 = {}, aS1 = {};
#pragma unroll
  for (int s = 0; s < KS3; ++s) {
    bf16x8 b = __builtin_bit_cast(bf16x8, bcur[s]);
    aS0 = __builtin_amdgcn_mfma_f32_16x16x32_bf16(af0[s], b, aS0, 0, 0, 0);
    aS1 = __builtin_amdgcn_mfma_f32_16x16x32_bf16(af1[s], b, aS1, 0, 0, 0);
  }
  // C layout 16x16: col = lane&15, row = (lane>>4)*4 + r
  if (c < 8) {
#pragma unroll
    for (int r = 0; r < 4; ++r) {
      const int R0 = wrow + q * 4 + r, R1 = R0 + 16;
      out_rel[(size_t)(brow + R0) * 8 + c] = fabsf(aS0[r]);
      out_rel[(size_t)(brow + R1) * 8 + c] = fabsf(aS1[r]);
      soutv[R0][c] = fast_sigmoid(aS0[r]);
      soutv[R1][c] = fast_sigmoid(aS1[r]);
    }
  }
  // same-wave LDS producer/consumer -> lgkmcnt-ordered, no barrier (verified).

  // ---- per-row records: Ml in regs, Mt into LDS ----------------------------
  float Ml0[4], Ml1[4];
#pragma unroll
  for (int rr = 0; rr < 8; ++rr) {
    const int R = wrow + (rr & 4) * 4 + q * 4 + (rr & 3);
    f32x2a p01 = *reinterpret_cast<const f32x2a*>(&soutv[R][0]);
    f32x2a p23 = *reinterpret_cast<const f32x2a*>(&soutv[R][2]);
    f32x2a p45 = *reinterpret_cast<const f32x2a*>(&soutv[R][4]);
    f32x2a p67 = *reinterpret_cast<const f32x2a*>(&soutv[R][6]);
    float m = 0.99999f;
    m *= (c & 1) ? p01[0] : 1.0f - p01[0];
    m *= (c & 2) ? p01[1] : 1.0f - p01[1];
    m *= (c & 4) ? p23[0] : 1.0f - p23[0];
    m *= (c & 8) ? p23[1] : 1.0f - p23[1];
    if (rr < 4) Ml0[rr & 3] = m; else Ml1[rr & 3] = m;
    float mt = (c & 1) ? p45[0] : 1.0f - p45[0];
    mt *= (c & 2) ? p45[1] : 1.0f - p45[1];
    mt *= (c & 4) ? p67[0] : 1.0f - p67[0];
    mt *= (c & 8) ? p67[1] : 1.0f - p67[1];
    mtrec[R][c] = mt;
  }

  float ans0[4] = {0, 0, 0, 0}, ans1[4] = {0, 0, 0, 0};

  // ---- D tiles, single-tile loop with register double-buffer ---------------
#pragma unroll 1
  for (int t = 0; t < 16; ++t) {
    f32x4 A0 = {}, A1 = {};
#pragma unroll
    for (int s = 0; s < KS3; ++s) {
      bf16x8 b = __builtin_bit_cast(bf16x8, bnxt[s]);
      A0 = __builtin_amdgcn_mfma_f32_16x16x32_bf16(af0[s], b, A0, 0, 0, 0);
      A1 = __builtin_amdgcn_mfma_f32_16x16x32_bf16(af1[s], b, A1, 0, 0, 0);
    }
    const int tn = (t < 15) ? t + 1 : 15;  // prefetch next tile
#pragma unroll
    for (int s = 0; s < 3; ++s) bnxt[s] = wsv[(tn * KS3 + s) * 64 + l];
#pragma unroll
    for (int r = 0; r < 4; ++r) {
      const int R0 = wrow + q * 4 + r, R1 = R0 + 16;
      float w0 = mtrec[R0][t];             // broadcast per 16-lane group
      float w1 = mtrec[R1][t];
      ans0[r] = fmaf(sig_prescaled(A0[r]), w0, ans0[r]);
      ans1[r] = fmaf(sig_prescaled(A1[r]), w1, ans1[r]);
    }
  }

  // ---- apply Ml, 16-lane DPP reduce, vectorized store ----------------------
#pragma unroll
  for (int r = 0; r < 4; ++r) {
    ans0[r] = reduce16(Ml0[r] * ans0[r]);
    ans1[r] = reduce16(Ml1[r] * ans1[r]);
  }
  if (c == 0) {
    f32x4 o0 = { ans0[0], ans0[1], ans0[2], ans0[3] };
    f32x4 o1 = { ans1[0], ans1[1], ans1[2], ans1[3] };
    *reinterpret_cast<f32x4*>(&out_ans[brow + wrow + q * 4])      = o0;
    *reinterpret_cast<f32x4*>(&out_ans[brow + wrow + 16 + q * 4]) = o1;
  }
}

extern "C" void kernel_launch(void* const* d_in, const int* in_sizes, int n_in,
                              void* d_out, int out_size, void* d_ws, size_t ws_size,
                              hipStream_t stream) {
  const float* phi = (const float*)d_in[0];
  const float* W_S = (const float*)d_in[1];
  const float* b_S = (const float*)d_in[2];
  const float* W_D = (const float*)d_in[3];
  const float* b_D = (const float*)d_in[4];
  const int rows = in_sizes[0] / F;        // 262144
  unsigned short* wsb = (unsigned short*)d_ws;   // 52224 B used
  float* out_ans = (float*)d_out;
  float* out_rel = out_ans + rows;
  hipLaunchKernelGGL(prep_w, dim3(NTT * KS3), dim3(64), 0, stream,
                     W_S, b_S, W_D, b_D, wsb);
  hipLaunchKernelGGL(mpuf_main, dim3(rows / RPB), dim3(256), 0, stream,
                     phi, wsb, out_ans, out_rel);
}